// Round 5
// baseline (312.489 us; speedup 1.0000x reference)
//
#include <hip/hip_runtime.h>
#include <hip/hip_bf16.h>

// B=4, L=S=1024, D=1024, H=16, HD=64.
// World model: float inputs FP32 (R4 direct-fp32 read gave finite sane output;
// bf16 misread would NaN). OUTPUT FP32 (R3/R4 absmax 0.541 == sqrt(2)*refmax,
// bit-identical across two different staging paths == correct pipeline read
// through the wrong dtype lens: bf16-packed buffer read as fp32 decorrelates
// with same stats; harness memsets upper half to 0 -> <=0.387 there).
// Mask: classifier (int32/byte/bf16/fp32) -> bytes. Pipeline: QKV GEMM (bf16
// MFMA, fp32 staging-convert) -> flash attention -> O GEMM writing fp32.

typedef __bf16 bf16;
typedef __bf16 bf16x8 __attribute__((ext_vector_type(8)));
typedef float floatx4 __attribute__((ext_vector_type(4)));

#define D_MODEL 1024
#define NHEAD   16
#define HDIM    64
#define BATCH   4
#define SEQ     1024
#define M_ROWS  (BATCH * SEQ)         // 4096
#define ACT_N   (M_ROWS * D_MODEL)    // 4194304

// async global->LDS, 16B per lane; LDS base wave-uniform (lane*16 added by HW)
#define GLD(gp, lp) __builtin_amdgcn_global_load_lds( \
    (__attribute__((address_space(1))) void*)(gp), \
    (__attribute__((address_space(3))) void*)(lp), 16, 0, 0)

// ---------------------------------------------------------------------------
// Mask classification. flags[1]: 1=int32, 0=byte, 2=bf16, 3=fp32.
// ---------------------------------------------------------------------------
__global__ __launch_bounds__(256)
void k_mclass(const unsigned* __restrict__ m, int* __restrict__ flags)
{
    __shared__ unsigned viol[4];   // [0] word>1, [1] byte>1, [2] half-bad, [3] lo!=0
    if (threadIdx.x < 4) viol[threadIdx.x] = 0;
    __syncthreads();
    unsigned a = 0, b = 0, c = 0, d = 0;
    for (int i = threadIdx.x; i < 1024; i += 256) {
        unsigned v = m[i];
        if (v > 1u) a = 1;
        if (((v & 0xFFu) > 1u) || (((v >> 8) & 0xFFu) > 1u) ||
            (((v >> 16) & 0xFFu) > 1u) || (((v >> 24) & 0xFFu) > 1u)) b = 1;
        unsigned lo = v & 0xFFFFu, hi = v >> 16;
        if (!((lo == 0u || lo == 0x3F80u) && (hi == 0u || hi == 0x3F80u))) c = 1;
        if (lo != 0u) d = 1;
    }
    if (a) atomicOr(&viol[0], 1u);
    if (b) atomicOr(&viol[1], 1u);
    if (c) atomicOr(&viol[2], 1u);
    if (d) atomicOr(&viol[3], 1u);
    __syncthreads();
    if (threadIdx.x == 0) {
        int fm;
        if (!viol[0])      fm = 1;                 // int32
        else if (!viol[1]) fm = 0;                 // bytes
        else if (!viol[2]) fm = viol[3] ? 2 : 3;   // bf16 : fp32
        else               fm = 0;                 // fallback
        flags[1] = fm;
    }
}

__global__ __launch_bounds__(256)
void k_maskconv(const void* __restrict__ msrc, unsigned char* __restrict__ mdst,
                const int* __restrict__ flags)
{
    const int s = blockIdx.x * 256 + threadIdx.x;   // grid 16*256 = 4096
    const int fm = flags[1];
    unsigned char v;
    if (fm == 1)      v = ((const int*)msrc)[s] != 0;
    else if (fm == 2) v = ((const unsigned short*)msrc)[s] != 0;
    else if (fm == 3) v = ((const unsigned*)msrc)[s] != 0;
    else              v = ((const unsigned char*)msrc)[s] != 0;
    mdst[s] = v;
}

// ---------------------------------------------------------------------------
// GEMM: C[M,1024] = A[M,K=1024] @ W[1024,K]^T + bias, fp32 acc, CT output.
// fp32 operands converted to bf16 in-register during LDS staging; bf16
// operands staged via async global_load_lds. 128x128 tile, BK=32, 256 thr.
// ---------------------------------------------------------------------------
template<bool AF32, bool BF32, typename CT>
__device__ __forceinline__ void gemm_core(const void* __restrict__ Av,
                                          const void* __restrict__ Wv,
                                          const float* __restrict__ bias,
                                          CT* __restrict__ C)
{
    __shared__ alignas(16) bf16 As[128 * 32];
    __shared__ alignas(16) bf16 Bs[128 * 32];

    const int t    = threadIdx.x;
    const int lane = t & 63;
    const int w    = t >> 6;
    const int wm   = w >> 1, wn = w & 1;
    const int l15  = lane & 15;
    const int quad = lane >> 4;
    const int m0   = blockIdx.y * 128;
    const int n0   = blockIdx.x * 128;

    floatx4 acc[4][4] = {};

    for (int k0 = 0; k0 < D_MODEL; k0 += 32) {
        #pragma unroll
        for (int i = 0; i < 2; ++i) {
            int c   = i * 256 + t;
            int row = c >> 2, cb = (c & 3) * 8;
            if (AF32) {
                const float* ga = (const float*)Av + (size_t)(m0 + row) * D_MODEL + k0 + cb;
                float4 f0 = ((const float4*)ga)[0];
                float4 f1 = ((const float4*)ga)[1];
                bf16x8 bv;
                bv[0] = (bf16)f0.x; bv[1] = (bf16)f0.y; bv[2] = (bf16)f0.z; bv[3] = (bf16)f0.w;
                bv[4] = (bf16)f1.x; bv[5] = (bf16)f1.y; bv[6] = (bf16)f1.z; bv[7] = (bf16)f1.w;
                *(bf16x8*)&As[row * 32 + cb] = bv;
            } else {
                const bf16* ga = (const bf16*)Av + (size_t)(m0 + row) * D_MODEL + k0 + cb;
                GLD(ga, As + (i * 256 + w * 64) * 8);   // == As[row*32+cb] per-lane
            }
            if (BF32) {
                const float* gb = (const float*)Wv + (size_t)(n0 + row) * D_MODEL + k0 + cb;
                float4 f0 = ((const float4*)gb)[0];
                float4 f1 = ((const float4*)gb)[1];
                bf16x8 bv;
                bv[0] = (bf16)f0.x; bv[1] = (bf16)f0.y; bv[2] = (bf16)f0.z; bv[3] = (bf16)f0.w;
                bv[4] = (bf16)f1.x; bv[5] = (bf16)f1.y; bv[6] = (bf16)f1.z; bv[7] = (bf16)f1.w;
                *(bf16x8*)&Bs[row * 32 + cb] = bv;
            } else {
                const bf16* gb = (const bf16*)Wv + (size_t)(n0 + row) * D_MODEL + k0 + cb;
                GLD(gb, Bs + (i * 256 + w * 64) * 8);
            }
        }
        __syncthreads();

        bf16x8 af[4], bfr[4];
        #pragma unroll
        for (int i = 0; i < 4; ++i)
            af[i] = *(const bf16x8*)&As[(wm * 64 + i * 16 + l15) * 32 + quad * 8];
        #pragma unroll
        for (int j = 0; j < 4; ++j)
            bfr[j] = *(const bf16x8*)&Bs[(wn * 64 + j * 16 + l15) * 32 + quad * 8];

        #pragma unroll
        for (int i = 0; i < 4; ++i)
            #pragma unroll
            for (int j = 0; j < 4; ++j)
                acc[i][j] = __builtin_amdgcn_mfma_f32_16x16x32_bf16(
                    af[i], bfr[j], acc[i][j], 0, 0, 0);
        __syncthreads();
    }

    // epilogue: C/D layout col=lane&15, row=quad*4+r
    #pragma unroll
    for (int i = 0; i < 4; ++i) {
        int row = m0 + wm * 64 + i * 16 + quad * 4;
        #pragma unroll
        for (int j = 0; j < 4; ++j) {
            int col = n0 + wn * 64 + j * 16 + l15;
            float bv = bias[col];
            #pragma unroll
            for (int r = 0; r < 4; ++r)
                C[(size_t)(row + r) * D_MODEL + col] = (CT)(acc[i][j][r] + bv);
        }
    }
}

__global__ __launch_bounds__(256)
void k_gemm_qkv(const float* __restrict__ q, const float* __restrict__ k,
                const float* __restrict__ v,
                const float* __restrict__ wq, const float* __restrict__ wk,
                const float* __restrict__ wv,
                const float* __restrict__ bq, const float* __restrict__ bk,
                const float* __restrict__ bv, bf16* __restrict__ o)
{
    const int z = blockIdx.z;
    const float* A  = (z == 0) ? q  : (z == 1) ? k  : v;
    const float* W  = (z == 0) ? wq : (z == 1) ? wk : wv;
    const float* bb = (z == 0) ? bq : (z == 1) ? bk : bv;
    gemm_core<true, true, bf16>(A, W, bb, o + (size_t)z * ACT_N);
}

__global__ __launch_bounds__(256)
void k_gemm_o(const bf16* __restrict__ A, const float* __restrict__ W,
              const float* __restrict__ bb, float* __restrict__ C)
{
    gemm_core<false, true, float>(A, W, bb, C);   // FP32 output to d_out
}

// ---------------------------------------------------------------------------
// Flash attention: grid (L/64, B*H), 256 threads (4 waves). Wave owns 16 q
// rows; S swept in 64-wide tiles; 16x16x32 bf16 MFMA for QK^T and PV.
// ---------------------------------------------------------------------------
__global__ __launch_bounds__(256)
void k_attn(const bf16* __restrict__ qkv, const unsigned char* __restrict__ mask,
            bf16* __restrict__ ctx)
{
    const bf16* qp = qkv;
    const bf16* kp = qkv + (size_t)1 * ACT_N;
    const bf16* vp = qkv + (size_t)2 * ACT_N;

    __shared__ alignas(16) bf16 Qs[64 * 64];
    __shared__ alignas(16) bf16 Ks[64 * 64];
    __shared__ alignas(16) bf16 Vt[64][80];
    __shared__ alignas(16) bf16 Ps[4][16][80];

    const int t    = threadIdx.x;
    const int lane = t & 63;
    const int w    = t >> 6;
    const int l15  = lane & 15;
    const int quad = lane >> 4;

    const int q0 = blockIdx.x * 64;
    const int b  = blockIdx.y >> 4;
    const int h  = blockIdx.y & 15;

    const size_t qbase = ((size_t)(b * SEQ + q0)) * D_MODEL + h * HDIM;
    const size_t kbase = ((size_t)(b * SEQ)) * D_MODEL + h * HDIM;

    #pragma unroll
    for (int i = 0; i < 2; ++i) {
        int c = i * 256 + t;
        int row = c >> 3, cb = (c & 7) * 8;
        GLD(qp + qbase + (size_t)row * D_MODEL + cb, Qs + (i * 256 + w * 64) * 8);
    }
    __syncthreads();

    bf16x8 qf[2];
    #pragma unroll
    for (int kk = 0; kk < 2; ++kk)
        qf[kk] = *(const bf16x8*)&Qs[(w * 16 + l15) * 64 + kk * 32 + quad * 8];

    floatx4 o[4] = {};
    float m_st[4], l_st[4];
    #pragma unroll
    for (int r = 0; r < 4; ++r) { m_st[r] = -1e30f; l_st[r] = 0.f; }

    const unsigned char* mrow = mask + b * SEQ;

    for (int s0 = 0; s0 < SEQ; s0 += 64) {
        __syncthreads();
        #pragma unroll
        for (int i = 0; i < 2; ++i) {
            int c = i * 256 + t;
            int row = c >> 3, cb = (c & 7) * 8;
            GLD(kp + kbase + (size_t)(s0 + row) * D_MODEL + cb,
                Ks + (i * 256 + w * 64) * 8);
            uint4 vv = *(const uint4*)(vp + kbase + (size_t)(s0 + row) * D_MODEL + cb);
            const bf16* ve = (const bf16*)&vv;
            #pragma unroll
            for (int j = 0; j < 8; ++j) Vt[cb + j][row] = ve[j];
        }
        __syncthreads();

        floatx4 s_acc[4] = {};
        #pragma unroll
        for (int j = 0; j < 4; ++j)
            #pragma unroll
            for (int kk = 0; kk < 2; ++kk) {
                bf16x8 kf = *(const bf16x8*)&Ks[(j * 16 + l15) * 64 + kk * 32 + quad * 8];
                s_acc[j] = __builtin_amdgcn_mfma_f32_16x16x32_bf16(
                    qf[kk], kf, s_acc[j], 0, 0, 0);
            }

        float sc[4][4];
        #pragma unroll
        for (int j = 0; j < 4; ++j) {
            int mk = mrow[s0 + j * 16 + l15];
            #pragma unroll
            for (int r = 0; r < 4; ++r)
                sc[j][r] = mk ? -1e30f : s_acc[j][r] * 0.125f;
        }

        float tm[4];
        #pragma unroll
        for (int r = 0; r < 4; ++r)
            tm[r] = fmaxf(fmaxf(sc[0][r], sc[1][r]), fmaxf(sc[2][r], sc[3][r]));
        #pragma unroll
        for (int mstep = 1; mstep <= 8; mstep <<= 1)
            #pragma unroll
            for (int r = 0; r < 4; ++r)
                tm[r] = fmaxf(tm[r], __shfl_xor(tm[r], mstep));

        float al[4], psum[4];
        #pragma unroll
        for (int r = 0; r < 4; ++r) {
            float mn = fmaxf(m_st[r], tm[r]);
            al[r] = __expf(m_st[r] - mn);
            m_st[r] = mn;
            psum[r] = 0.f;
        }

        #pragma unroll
        for (int j = 0; j < 4; ++j)
            #pragma unroll
            for (int r = 0; r < 4; ++r) {
                float p = (sc[j][r] <= -1e29f) ? 0.f : __expf(sc[j][r] - m_st[r]);
                psum[r] += p;
                Ps[w][quad * 4 + r][j * 16 + l15] = (bf16)p;
            }
        #pragma unroll
        for (int mstep = 1; mstep <= 8; mstep <<= 1)
            #pragma unroll
            for (int r = 0; r < 4; ++r)
                psum[r] += __shfl_xor(psum[r], mstep);
        #pragma unroll
        for (int r = 0; r < 4; ++r)
            l_st[r] = l_st[r] * al[r] + psum[r];

        #pragma unroll
        for (int j = 0; j < 4; ++j)
            #pragma unroll
            for (int r = 0; r < 4; ++r)
                o[j][r] *= al[r];

        __builtin_amdgcn_wave_barrier();
        bf16x8 pf[2];
        #pragma unroll
        for (int kk = 0; kk < 2; ++kk)
            pf[kk] = *(const bf16x8*)&Ps[w][l15][kk * 32 + quad * 8];
        #pragma unroll
        for (int j = 0; j < 4; ++j)
            #pragma unroll
            for (int kk = 0; kk < 2; ++kk) {
                bf16x8 vf = *(const bf16x8*)&Vt[j * 16 + l15][kk * 32 + quad * 8];
                o[j] = __builtin_amdgcn_mfma_f32_16x16x32_bf16(
                    pf[kk], vf, o[j], 0, 0, 0);
            }
    }

    float inv[4];
    #pragma unroll
    for (int r = 0; r < 4; ++r) inv[r] = (l_st[r] > 0.f) ? 1.f / l_st[r] : 0.f;
    #pragma unroll
    for (int j = 0; j < 4; ++j)
        #pragma unroll
        for (int r = 0; r < 4; ++r) {
            int row = q0 + w * 16 + quad * 4 + r;
            int col = h * HDIM + j * 16 + l15;
            ctx[((size_t)(b * SEQ + row)) * D_MODEL + col] = (bf16)(o[j][r] * inv[r]);
        }
}

// ---------------------------------------------------------------------------
extern "C" void kernel_launch(void* const* d_in, const int* in_sizes, int n_in,
                              void* d_out, int out_size, void* d_ws, size_t ws_size,
                              hipStream_t stream)
{
    // ws: [0,16) flags | [4096,8192) mask bytes | [65536,+24MB) qkv bf16 |
    //     then ctx bf16 8MB.  Total ~33.6MB.
    char* wsb = (char*)d_ws;
    int* flags = (int*)wsb;
    unsigned char* mb = (unsigned char*)(wsb + 4096);
    bf16* qkv = (bf16*)(wsb + 65536);
    bf16* ctx = qkv + (size_t)3 * ACT_N;
    float* out = (float*)d_out;   // FP32 output (world-model R4 correction)

    const float* query = (const float*)d_in[0];
    const float* key_  = (const float*)d_in[1];
    const float* value = (const float*)d_in[2];
    const float* Wq    = (const float*)d_in[4];
    const float* bq    = (const float*)d_in[5];
    const float* Wk    = (const float*)d_in[6];
    const float* bk    = (const float*)d_in[7];
    const float* Wv    = (const float*)d_in[8];
    const float* bv    = (const float*)d_in[9];
    const float* Wo    = (const float*)d_in[10];
    const float* bo    = (const float*)d_in[11];

    k_mclass<<<1, 256, 0, stream>>>((const unsigned*)d_in[3], flags);
    k_maskconv<<<16, 256, 0, stream>>>(d_in[3], mb, flags);

    dim3 blk(256);
    k_gemm_qkv<<<dim3(8, 32, 3), blk, 0, stream>>>(query, key_, value,
                                                   Wq, Wk, Wv, bq, bk, bv, qkv);
    k_attn<<<dim3(16, 64), blk, 0, stream>>>(qkv, mb, ctx);
    k_gemm_o<<<dim3(8, 32), blk, 0, stream>>>(ctx, Wo, bo, out);
}

// Round 7
// 240.921 us; speedup vs baseline: 1.2971x; 1.2971x over previous
//
#include <hip/hip_runtime.h>
#include <hip/hip_bf16.h>

// B=4, L=S=1024, D=1024, H=16, HD=64. Inputs fp32, output fp32, mask bool-ish
// (runtime-classified). R5 passed at 312us; R6/R7 attacks: (1) k_attn bank
// conflicts (2.3e7) via fragment-ordered GLD staging + V-projection computed
// directly transposed (a gemm_bt with row bias) + P stored in A-frag order;
// (2) no-max exp2 softmax with l computed by MFMA against a ones-fragment;
// (3) GEMMs on the all-GLD bf16 path after one fused fp32->bf16 convert.
// R6->R7: __exp2f doesn't exist in HIP -> __builtin_amdgcn_exp2f (v_exp_f32).

typedef __bf16 bf16;
typedef __bf16 bf16x8 __attribute__((ext_vector_type(8)));
typedef float floatx4 __attribute__((ext_vector_type(4)));

#define D_MODEL 1024
#define NHEAD   16
#define HDIM    64
#define BATCH   4
#define SEQ     1024
#define M_ROWS  (BATCH * SEQ)         // 4096
#define ACT_N   ((size_t)M_ROWS * D_MODEL)    // 4M
#define W_N     ((size_t)D_MODEL * D_MODEL)   // 1M
#define SC2     0.18033688011112042f  // 0.125 * log2(e)

#define GLD(gp, lp) __builtin_amdgcn_global_load_lds( \
    (__attribute__((address_space(1))) void*)(gp), \
    (__attribute__((address_space(3))) void*)(lp), 16, 0, 0)

// ---------------------------------------------------------------------------
// Mask: classify dtype (int32/byte/bf16/fp32) then emit float bias 0 / -1e30.
// One block.
// ---------------------------------------------------------------------------
__global__ __launch_bounds__(256)
void k_mask(const unsigned* __restrict__ m, float* __restrict__ mbias)
{
    __shared__ unsigned viol[4];
    __shared__ int fmsh;
    if (threadIdx.x < 4) viol[threadIdx.x] = 0;
    __syncthreads();
    unsigned a = 0, b = 0, c = 0, d = 0;
    for (int i = threadIdx.x; i < 1024; i += 256) {
        unsigned v = m[i];
        if (v > 1u) a = 1;
        if (((v & 0xFFu) > 1u) || (((v >> 8) & 0xFFu) > 1u) ||
            (((v >> 16) & 0xFFu) > 1u) || (((v >> 24) & 0xFFu) > 1u)) b = 1;
        unsigned lo = v & 0xFFFFu, hi = v >> 16;
        if (!((lo == 0u || lo == 0x3F80u) && (hi == 0u || hi == 0x3F80u))) c = 1;
        if (lo != 0u) d = 1;
    }
    if (a) atomicOr(&viol[0], 1u);
    if (b) atomicOr(&viol[1], 1u);
    if (c) atomicOr(&viol[2], 1u);
    if (d) atomicOr(&viol[3], 1u);
    __syncthreads();
    if (threadIdx.x == 0) {
        int fm;
        if (!viol[0])      fm = 1;                 // int32
        else if (!viol[1]) fm = 0;                 // bytes
        else if (!viol[2]) fm = viol[3] ? 2 : 3;   // bf16 : fp32
        else               fm = 0;
        fmsh = fm;
    }
    __syncthreads();
    const int fm = fmsh;
    for (int i = 0; i < 16; ++i) {
        int s = i * 256 + threadIdx.x;   // 4096 mask elements
        bool msk;
        if (fm == 1)      msk = ((const int*)m)[s] != 0;
        else if (fm == 2) msk = ((const unsigned short*)m)[s] != 0;
        else if (fm == 3) msk = ((const unsigned*)m)[s] != 0;
        else              msk = ((const unsigned char*)m)[s] != 0;
        mbias[s] = msk ? -1e30f : 0.f;
    }
}

// ---------------------------------------------------------------------------
// Fused fp32->bf16 convert: q,k,v (4M each) then Wq,Wk,Wv,Wo (1M each) into
// one contiguous 16M-element bf16 region. 8 elems/thread.
// ---------------------------------------------------------------------------
__global__ __launch_bounds__(256)
void k_convert_all(const float* __restrict__ a0, const float* __restrict__ a1,
                   const float* __restrict__ a2,
                   const float* __restrict__ w0, const float* __restrict__ w1,
                   const float* __restrict__ w2, const float* __restrict__ w3,
                   bf16* __restrict__ dst)
{
    size_t i = ((size_t)blockIdx.x * 256 + threadIdx.x) * 8;
    const float* src; size_t off;
    if (i < ((size_t)12 << 20)) {
        int z = (int)(i >> 22);
        src = (z == 0) ? a0 : (z == 1) ? a1 : a2;
        off = i & (((size_t)1 << 22) - 1);
    } else {
        size_t r = i - ((size_t)12 << 20);
        int j = (int)(r >> 20);
        src = (j == 0) ? w0 : (j == 1) ? w1 : (j == 2) ? w2 : w3;
        off = r & (((size_t)1 << 20) - 1);
    }
    float4 f0 = ((const float4*)(src + off))[0];
    float4 f1 = ((const float4*)(src + off))[1];
    bf16x8 o;
    o[0] = (bf16)f0.x; o[1] = (bf16)f0.y; o[2] = (bf16)f0.z; o[3] = (bf16)f0.w;
    o[4] = (bf16)f1.x; o[5] = (bf16)f1.y; o[6] = (bf16)f1.z; o[7] = (bf16)f1.w;
    *(bf16x8*)(dst + i) = o;
}

// ---------------------------------------------------------------------------
// GEMM core (all-bf16, GLD staging): C[m0..+128, n0..+128] = A@W^T + bias.
// rowBias: bias indexed by output ROW (used for the transposed V projection).
// ---------------------------------------------------------------------------
template<typename CT>
__device__ __forceinline__ void gemm_core(const bf16* __restrict__ A,
                                          const bf16* __restrict__ W,
                                          const float* __restrict__ bias,
                                          CT* __restrict__ C,
                                          int m0, int n0, bool rowBias)
{
    __shared__ alignas(16) bf16 As[128 * 32];
    __shared__ alignas(16) bf16 Bs[128 * 32];

    const int t    = threadIdx.x;
    const int lane = t & 63;
    const int w    = t >> 6;
    const int wm   = w >> 1, wn = w & 1;
    const int l15  = lane & 15;
    const int quad = lane >> 4;

    floatx4 acc[4][4] = {};

    for (int k0 = 0; k0 < D_MODEL; k0 += 32) {
        #pragma unroll
        for (int i = 0; i < 2; ++i) {
            int c   = i * 256 + t;
            int row = c >> 2, cb = (c & 3) * 8;
            const bf16* ga = A + (size_t)(m0 + row) * D_MODEL + k0 + cb;
            const bf16* gb = W + (size_t)(n0 + row) * D_MODEL + k0 + cb;
            int lo = (i * 256 + w * 64) * 8;
            GLD(ga, As + lo);
            GLD(gb, Bs + lo);
        }
        __syncthreads();

        bf16x8 af[4], bfr[4];
        #pragma unroll
        for (int i = 0; i < 4; ++i)
            af[i] = *(const bf16x8*)&As[(wm * 64 + i * 16 + l15) * 32 + quad * 8];
        #pragma unroll
        for (int j = 0; j < 4; ++j)
            bfr[j] = *(const bf16x8*)&Bs[(wn * 64 + j * 16 + l15) * 32 + quad * 8];

        #pragma unroll
        for (int i = 0; i < 4; ++i)
            #pragma unroll
            for (int j = 0; j < 4; ++j)
                acc[i][j] = __builtin_amdgcn_mfma_f32_16x16x32_bf16(
                    af[i], bfr[j], acc[i][j], 0, 0, 0);
        __syncthreads();
    }

    #pragma unroll
    for (int i = 0; i < 4; ++i) {
        int rowb = m0 + wm * 64 + i * 16 + quad * 4;
        float bvr[4];
        if (rowBias) {
            #pragma unroll
            for (int r = 0; r < 4; ++r) bvr[r] = bias[rowb + r];
        }
        #pragma unroll
        for (int j = 0; j < 4; ++j) {
            int col = n0 + wn * 64 + j * 16 + l15;
            float bc = rowBias ? 0.f : bias[col];
            #pragma unroll
            for (int r = 0; r < 4; ++r) {
                float val = acc[i][j][r] + (rowBias ? bvr[r] : bc);
                C[(size_t)(rowb + r) * D_MODEL + col] = (CT)val;
            }
        }
    }
}

// Fused projection GEMM: blocks 0..511 = Q/K proj (4096x1024), 512..767 =
// transposed V proj per batch: Vt_b = Wv @ value_b^T (+bv by row).
__global__ __launch_bounds__(256)
void k_gemm_proj(const bf16* __restrict__ cq, const bf16* __restrict__ ck,
                 const bf16* __restrict__ cv,
                 const bf16* __restrict__ cWq, const bf16* __restrict__ cWk,
                 const bf16* __restrict__ cWv,
                 const float* __restrict__ bq, const float* __restrict__ bk,
                 const float* __restrict__ bv,
                 bf16* __restrict__ qproj, bf16* __restrict__ kproj,
                 bf16* __restrict__ vt)
{
    const int bid = blockIdx.x;
    if (bid < 512) {
        int z = bid >> 8, r = bid & 255;
        int n0 = (r & 7) * 128, m0 = (r >> 3) * 128;
        gemm_core<bf16>(z ? ck : cq, z ? cWk : cWq, z ? bk : bq,
                        z ? kproj : qproj, m0, n0, false);
    } else {
        int r = bid - 512;
        int b = r >> 6, r2 = r & 63;
        int n0 = (r2 & 7) * 128, m0 = (r2 >> 3) * 128;
        gemm_core<bf16>(cWv, cv + (size_t)b * W_N, bv,
                        vt + (size_t)b * W_N, m0, n0, true);
    }
}

__global__ __launch_bounds__(256)
void k_gemm_o(const bf16* __restrict__ A, const bf16* __restrict__ W,
              const float* __restrict__ bb, float* __restrict__ C)
{
    gemm_core<float>(A, W, bb, C, blockIdx.y * 128, blockIdx.x * 128, false);
}

// ---------------------------------------------------------------------------
// Flash attention, fragment-ordered LDS. Grid (L/64, B*H), 256 thr (4 waves),
// wave = 16 q rows. No-max exp2 softmax; l via MFMA with ones-B-fragment.
// ---------------------------------------------------------------------------
__global__ __launch_bounds__(256)
void k_attn(const bf16* __restrict__ qproj, const bf16* __restrict__ kproj,
            const bf16* __restrict__ vt, const float* __restrict__ mbias_g,
            bf16* __restrict__ ctx)
{
    __shared__ alignas(16) bf16 Qst[4096];   // [w*2+kk][lane]*8, frag order
    __shared__ alignas(16) bf16 Kst[4096];   // [f=j*2+kk][lane]*8
    __shared__ alignas(16) bf16 Vst[4096];
    __shared__ alignas(16) bf16 Past[4096];  // per-wave 1024, A-frag order
    __shared__ float MB[1024];

    const int t    = threadIdx.x;
    const int lane = t & 63;
    const int w    = t >> 6;
    const int l15  = lane & 15;
    const int quad = lane >> 4;

    const int q0 = blockIdx.x * 64;
    const int b  = blockIdx.y >> 4;
    const int h  = blockIdx.y & 15;

    // mask bias -> LDS
    #pragma unroll
    for (int i = 0; i < 4; ++i)
        MB[i * 256 + t] = mbias_g[b * SEQ + i * 256 + t];

    // Q stage, fragment order: lane fetches Q[q0 + w*16 + l15][kk*32+quad*8]
    #pragma unroll
    for (int kk = 0; kk < 2; ++kk) {
        const bf16* gp = qproj + (size_t)(b * SEQ + q0 + w * 16 + l15) * D_MODEL
                       + h * HDIM + kk * 32 + quad * 8;
        GLD(gp, Qst + (w * 2 + kk) * 512);
    }
    __syncthreads();

    bf16x8 qf[2];
    #pragma unroll
    for (int kk = 0; kk < 2; ++kk)
        qf[kk] = *(const bf16x8*)&Qst[(w * 2 + kk) * 512 + lane * 8];

    bf16x8 ones;
    #pragma unroll
    for (int e = 0; e < 8; ++e) ones[e] = (bf16)1.0f;

    floatx4 o[4] = {};
    floatx4 accl = {};

    // P-store base (bijective map into A-frag order)
    const int pbase = w * 1024 + (l15 >> 3) * 128 + quad * 32 + (l15 & 7);

    for (int s0 = 0; s0 < SEQ; s0 += 64) {
        __syncthreads();
        // K and Vt tiles, fragment order: wave w stages blocks f=2w, 2w+1
        #pragma unroll
        for (int i = 0; i < 2; ++i) {
            int f = w * 2 + i;
            int row = (f >> 1) * 16 + l15;          // s-row (K) / d-row (Vt)
            int cb  = (f & 1) * 32 + quad * 8;
            GLD(kproj + (size_t)(b * SEQ + s0 + row) * D_MODEL + h * HDIM + cb,
                Kst + f * 512);
            GLD(vt + (size_t)(b * 1024 + h * HDIM + row) * D_MODEL + s0 + cb,
                Vst + f * 512);
        }
        __syncthreads();

        // S = Q K^T
        floatx4 s_acc[4] = {};
        #pragma unroll
        for (int j = 0; j < 4; ++j)
            #pragma unroll
            for (int kk = 0; kk < 2; ++kk) {
                bf16x8 kf = *(const bf16x8*)&Kst[(j * 2 + kk) * 512 + lane * 8];
                s_acc[j] = __builtin_amdgcn_mfma_f32_16x16x32_bf16(
                    qf[kk], kf, s_acc[j], 0, 0, 0);
            }

        // P = exp2(s*SC2 + mbias)   (masked: bias -1e30 -> exp2 -> 0)
        #pragma unroll
        for (int j = 0; j < 4; ++j) {
            float mb = MB[s0 + j * 16 + l15];
            #pragma unroll
            for (int r = 0; r < 4; ++r) {
                float p = __builtin_amdgcn_exp2f(fmaf(s_acc[j][r], SC2, mb));
                Past[pbase + (j >> 1) * 512 + (j & 1) * 256 + r * 8] = (bf16)p;
            }
        }
        __builtin_amdgcn_wave_barrier();

        bf16x8 pf[2];
        #pragma unroll
        for (int kk = 0; kk < 2; ++kk)
            pf[kk] = *(const bf16x8*)&Past[w * 1024 + kk * 512 + lane * 8];

        // l += P . 1   (row-sums land in same C rows as O)
        #pragma unroll
        for (int kk = 0; kk < 2; ++kk)
            accl = __builtin_amdgcn_mfma_f32_16x16x32_bf16(pf[kk], ones, accl,
                                                           0, 0, 0);
        // O += P V
        #pragma unroll
        for (int j = 0; j < 4; ++j)
            #pragma unroll
            for (int kk = 0; kk < 2; ++kk) {
                bf16x8 vf = *(const bf16x8*)&Vst[(j * 2 + kk) * 512 + lane * 8];
                o[j] = __builtin_amdgcn_mfma_f32_16x16x32_bf16(
                    pf[kk], vf, o[j], 0, 0, 0);
            }
    }

    float inv[4];
    #pragma unroll
    for (int r = 0; r < 4; ++r) inv[r] = (accl[r] > 0.f) ? 1.f / accl[r] : 0.f;
    #pragma unroll
    for (int j = 0; j < 4; ++j)
        #pragma unroll
        for (int r = 0; r < 4; ++r) {
            int row = q0 + w * 16 + quad * 4 + r;
            int col = h * HDIM + j * 16 + l15;
            ctx[(size_t)(b * SEQ + row) * D_MODEL + col] = (bf16)(o[j][r] * inv[r]);
        }
}

// ---------------------------------------------------------------------------
extern "C" void kernel_launch(void* const* d_in, const int* in_sizes, int n_in,
                              void* d_out, int out_size, void* d_ws, size_t ws_size,
                              hipStream_t stream)
{
    // ws: [0,16K) mbias fp32 | [64K,+32MB) converted bf16 (q,k,v,Wq,Wk,Wv,Wo)
    //     | qproj 8MB | kproj 8MB | vt 8MB | ctx 8MB.   Total ~64.1MB.
    char* wsb = (char*)d_ws;
    float* mbias = (float*)wsb;
    bf16* cbase = (bf16*)(wsb + 65536);
    bf16 *cq = cbase, *ck = cq + ACT_N, *cv = ck + ACT_N;
    bf16 *cWq = cv + ACT_N, *cWk = cWq + W_N, *cWv = cWk + W_N, *cWo = cWv + W_N;
    bf16* qproj = cWo + W_N;
    bf16* kproj = qproj + ACT_N;
    bf16* vt    = kproj + ACT_N;
    bf16* ctx   = vt + ACT_N;
    float* out  = (float*)d_out;

    k_mask<<<1, 256, 0, stream>>>((const unsigned*)d_in[3], mbias);
    k_convert_all<<<8192, 256, 0, stream>>>(
        (const float*)d_in[0], (const float*)d_in[1], (const float*)d_in[2],
        (const float*)d_in[4], (const float*)d_in[6], (const float*)d_in[8],
        (const float*)d_in[10], cbase);

    k_gemm_proj<<<768, 256, 0, stream>>>(cq, ck, cv, cWq, cWk, cWv,
                                         (const float*)d_in[5],
                                         (const float*)d_in[7],
                                         (const float*)d_in[9],
                                         qproj, kproj, vt);
    k_attn<<<dim3(16, 64), 256, 0, stream>>>(qproj, kproj, vt, mbias, ctx);
    k_gemm_o<<<dim3(8, 32), 256, 0, stream>>>(ctx, cWo, (const float*)d_in[11], out);
}